// Round 1
// baseline (309.906 us; speedup 1.0000x reference)
//
#include <hip/hip_runtime.h>

#define NN 30000
#define NE 480000
#define CAP 96
#define SCALE 0.0625f

typedef __attribute__((ext_vector_type(8))) short bf16x8;
typedef __attribute__((ext_vector_type(4))) float f32x4;
typedef __attribute__((ext_vector_type(4))) int i32x4;

__device__ __forceinline__ unsigned short f2bf(float f) {
    unsigned int u = __float_as_uint(f);
    u = (u + 0x7fffu + ((u >> 16) & 1u)) >> 16;
    return (unsigned short)u;
}

// ---------------- LayerNorm -> bf16 x ----------------
__global__ __launch_bounds__(256) void ln_kernel(const float* __restrict__ s,
                                                 const float* __restrict__ gamma,
                                                 const float* __restrict__ beta,
                                                 unsigned short* __restrict__ xb) {
    const int n = blockIdx.x;
    const int c = threadIdx.x;
    float v = s[n * 256 + c];
    float sum = v, sq = v * v;
    for (int o = 32; o; o >>= 1) {
        sum += __shfl_down(sum, o, 64);
        sq  += __shfl_down(sq,  o, 64);
    }
    __shared__ float ssum[4], ssq[4];
    const int wave = c >> 6, lane = c & 63;
    if (lane == 0) { ssum[wave] = sum; ssq[wave] = sq; }
    __syncthreads();
    float ts = ssum[0] + ssum[1] + ssum[2] + ssum[3];
    float tq = ssq[0]  + ssq[1]  + ssq[2]  + ssq[3];
    float mu  = ts * (1.0f / 256.0f);
    float var = tq * (1.0f / 256.0f) - mu * mu;
    float x = (v - mu) * rsqrtf(var + 1e-5f) * gamma[c] + beta[c];
    xb[n * 256 + c] = f2bf(x);
}

// ---------------- Wqkv [256,768] f32 -> WT [768,256] bf16 ----------------
__global__ __launch_bounds__(256) void wt_kernel(const float* __restrict__ W,
                                                 unsigned short* __restrict__ WT) {
    const int idx = blockIdx.x * 256 + threadIdx.x;  // 768*256 = 196608
    if (idx < 768 * 256) {
        const int n = idx >> 8;     // 0..767
        const int k = idx & 255;    // 0..255
        WT[idx] = f2bf(W[k * 768 + n]);
    }
}

// ---------------- zero cursor ----------------
__global__ __launch_bounds__(256) void zero_kernel(int* __restrict__ p, int n) {
    const int i = blockIdx.x * 256 + threadIdx.x;
    if (i < n) p[i] = 0;
}

// ---------------- bucket edges by dst ----------------
__global__ __launch_bounds__(256) void scatter_kernel(const int* __restrict__ src,
                                                      const int* __restrict__ dst,
                                                      int* __restrict__ cursor,
                                                      int* __restrict__ col) {
    const int e = blockIdx.x * 256 + threadIdx.x;
    if (e < NE) {
        const int d = dst[e];
        const int slot = atomicAdd(&cursor[d], 1);
        if (slot < CAP) col[d * CAP + slot] = src[e];
    }
}

// ---------------- GEMM: qkv[30000,768] f32 = x_bf16 @ WT^T ----------------
#define BM 64
#define BN 64
#define BK 32
#define LDK 40  // padded k-stride (elements)

__global__ __launch_bounds__(256) void gemm_kernel(const unsigned short* __restrict__ A,  // [30000,256] bf16
                                                   const unsigned short* __restrict__ B,  // [768,256]  bf16 (n-major)
                                                   float* __restrict__ C) {               // [30000,768] f32
    __shared__ unsigned short As[BM * LDK];
    __shared__ unsigned short Bs[BN * LDK];
    const int tid  = threadIdx.x;
    const int lane = tid & 63;
    const int wave = tid >> 6;
    const int bm = blockIdx.x * BM;
    const int bn = blockIdx.y * BN;
    const int srow  = tid >> 2;        // 0..63
    const int skseg = (tid & 3) * 8;   // 0,8,16,24
    const int wm = (wave & 1) * 32;
    const int wn = (wave >> 1) * 32;
    const int l16  = lane & 15;
    const int quad = lane >> 4;

    f32x4 acc[2][2] = {};
    const int gm = bm + srow;
    const bool a_ok = (gm < NN);

    for (int kt = 0; kt < 256; kt += BK) {
        i32x4 va = {0, 0, 0, 0};
        if (a_ok) va = *(const i32x4*)(A + (size_t)gm * 256 + kt + skseg);
        *(i32x4*)(&As[srow * LDK + skseg]) = va;
        *(i32x4*)(&Bs[srow * LDK + skseg]) =
            *(const i32x4*)(B + (size_t)(bn + srow) * 256 + kt + skseg);
        __syncthreads();

        bf16x8 af[2], bfr[2];
        #pragma unroll
        for (int i = 0; i < 2; i++)
            af[i]  = *(const bf16x8*)(&As[(wm + i * 16 + l16) * LDK + quad * 8]);
        #pragma unroll
        for (int i = 0; i < 2; i++)
            bfr[i] = *(const bf16x8*)(&Bs[(wn + i * 16 + l16) * LDK + quad * 8]);
        #pragma unroll
        for (int i = 0; i < 2; i++)
            #pragma unroll
            for (int j = 0; j < 2; j++)
                acc[i][j] = __builtin_amdgcn_mfma_f32_16x16x32_bf16(af[i], bfr[j], acc[i][j], 0, 0, 0);
        __syncthreads();
    }

    #pragma unroll
    for (int i = 0; i < 2; i++)
        #pragma unroll
        for (int j = 0; j < 2; j++)
            #pragma unroll
            for (int r = 0; r < 4; r++) {
                const int row = bm + wm + i * 16 + quad * 4 + r;
                const int ccol = bn + wn + j * 16 + l16;
                if (row < NN) C[(size_t)row * 768 + ccol] = acc[i][j][r];
            }
}

// ---------------- per-dst softmax + weighted aggregate ----------------
__global__ __launch_bounds__(256) void edge_kernel(const float* __restrict__ qkv,
                                                   const int* __restrict__ cursor,
                                                   const int* __restrict__ col,
                                                   float* __restrict__ out) {
    const int n = blockIdx.x;
    const int c = threadIdx.x;
    int deg = cursor[n];
    if (deg > CAP) deg = CAP;

    __shared__ int sidx[CAP];
    if (c < deg) sidx[c] = col[n * CAP + c];
    __syncthreads();

    const float kk = qkv[(size_t)n * 768 + 256 + c] * SCALE;
    float z = 0.0f, acc = 0.0f;
    for (int i = 0; i < deg; ++i) {
        const int s = sidx[i];
        const float qv = qkv[(size_t)s * 768 + c];
        const float vv = qkv[(size_t)s * 768 + 512 + c];
        const float w = __expf(qv * kk);
        z += w;
        acc += w * vv;
    }
    out[n * 256 + c] = (deg > 0) ? (acc / z) : 0.0f;
}

extern "C" void kernel_launch(void* const* d_in, const int* in_sizes, int n_in,
                              void* d_out, int out_size, void* d_ws, size_t ws_size,
                              hipStream_t stream) {
    const float* s     = (const float*)d_in[0];
    const float* Wqkv  = (const float*)d_in[1];
    const float* gamma = (const float*)d_in[2];
    const float* beta  = (const float*)d_in[3];
    const int*   src   = (const int*)d_in[4];
    const int*   dst   = (const int*)d_in[5];
    float* out = (float*)d_out;

    char* ws = (char*)d_ws;
    unsigned short* xb  = (unsigned short*)(ws);                    // 15,360,000 B
    unsigned short* WT  = (unsigned short*)(ws + 15360000);         //    393,216 B
    float*          qkv = (float*)(ws + 15753216);                  // 92,160,000 B
    int*            cur = (int*)(ws + 107913216);                   //    120,000 B
    int*            col = (int*)(ws + 108033280);                   // 11,520,000 B  (total ~119.6 MB)

    ln_kernel<<<NN, 256, 0, stream>>>(s, gamma, beta, xb);
    wt_kernel<<<(768 * 256 + 255) / 256, 256, 0, stream>>>(Wqkv, WT);
    zero_kernel<<<(NN + 255) / 256, 256, 0, stream>>>(cur, NN);
    scatter_kernel<<<(NE + 255) / 256, 256, 0, stream>>>(src, dst, cur, col);
    gemm_kernel<<<dim3((NN + BM - 1) / BM, 768 / BN), 256, 0, stream>>>(xb, WT, qkv);
    edge_kernel<<<NN, 256, 0, stream>>>(qkv, cur, col, out);
}

// Round 2
// 238.504 us; speedup vs baseline: 1.2994x; 1.2994x over previous
//
#include <hip/hip_runtime.h>
#include <string.h>

#define NN 30000
#define NE 480000
#define CAP 96
#define SCALE 0.0625f

typedef __attribute__((ext_vector_type(8))) _Float16 f16x8;
typedef __attribute__((ext_vector_type(4))) float f32x4;
typedef __attribute__((ext_vector_type(4))) int i32x4;

__device__ __forceinline__ unsigned short f2h(float f) {
    _Float16 h = (_Float16)f;
    unsigned short u;
    memcpy(&u, &h, 2);
    return u;
}
__device__ __forceinline__ float h2f(unsigned short u) {
    _Float16 h;
    memcpy(&h, &u, 2);
    return (float)h;
}

// ---------------- LayerNorm -> fp16 x ----------------
__global__ __launch_bounds__(256) void ln_kernel(const float* __restrict__ s,
                                                 const float* __restrict__ gamma,
                                                 const float* __restrict__ beta,
                                                 unsigned short* __restrict__ xh) {
    const int n = blockIdx.x;
    const int c = threadIdx.x;
    float v = s[n * 256 + c];
    float sum = v, sq = v * v;
    for (int o = 32; o; o >>= 1) {
        sum += __shfl_down(sum, o, 64);
        sq  += __shfl_down(sq,  o, 64);
    }
    __shared__ float ssum[4], ssq[4];
    const int wave = c >> 6, lane = c & 63;
    if (lane == 0) { ssum[wave] = sum; ssq[wave] = sq; }
    __syncthreads();
    float ts = ssum[0] + ssum[1] + ssum[2] + ssum[3];
    float tq = ssq[0]  + ssq[1]  + ssq[2]  + ssq[3];
    float mu  = ts * (1.0f / 256.0f);
    float var = tq * (1.0f / 256.0f) - mu * mu;
    float x = (v - mu) * rsqrtf(var + 1e-5f) * gamma[c] + beta[c];
    xh[n * 256 + c] = f2h(x);
}

// ---------------- Wqkv [256,768] f32 -> WT [768,256] fp16 ----------------
__global__ __launch_bounds__(256) void wt_kernel(const float* __restrict__ W,
                                                 unsigned short* __restrict__ WT) {
    const int idx = blockIdx.x * 256 + threadIdx.x;
    if (idx < 768 * 256) {
        const int n = idx >> 8;
        const int k = idx & 255;
        WT[idx] = f2h(W[k * 768 + n]);
    }
}

__global__ __launch_bounds__(256) void zero_kernel(int* __restrict__ p, int n) {
    const int i = blockIdx.x * 256 + threadIdx.x;
    if (i < n) p[i] = 0;
}

__global__ __launch_bounds__(256) void scatter_kernel(const int* __restrict__ src,
                                                      const int* __restrict__ dst,
                                                      int* __restrict__ cursor,
                                                      int* __restrict__ col) {
    const int e = blockIdx.x * 256 + threadIdx.x;
    if (e < NE) {
        const int d = dst[e];
        const int slot = atomicAdd(&cursor[d], 1);
        if (slot < CAP) col[d * CAP + slot] = src[e];
    }
}

// ---------------- GEMM: fp16 128x128 tile, writes qv-interleaved + k ----------------
#define BM 128
#define BN 128
#define BK 32
#define LDK 40  // padded k-stride (fp16 elements)

__global__ __launch_bounds__(256) void gemm_kernel(const unsigned short* __restrict__ A,   // [30000,256] fp16
                                                   const unsigned short* __restrict__ B,   // [768,256]   fp16 (n-major)
                                                   unsigned short* __restrict__ qv,        // [30000,256,2] fp16 {q,v}
                                                   unsigned short* __restrict__ kb) {      // [30000,256]  fp16 k
    __shared__ unsigned short As[BM * LDK];
    __shared__ unsigned short Bs[BN * LDK];
    const int tid  = threadIdx.x;
    const int lane = tid & 63;
    const int wave = tid >> 6;
    const int bm = blockIdx.x * BM;
    const int bn = blockIdx.y * BN;
    const int srow = tid >> 2;          // 0..63 (plus +64 second pass)
    const int kseg = (tid & 3) * 8;     // 0,8,16,24
    const int wm = (wave & 1) * 64;
    const int wn = (wave >> 1) * 64;
    const int l16  = lane & 15;
    const int quad = lane >> 4;

    f32x4 acc[4][4] = {};

    for (int kt = 0; kt < 256; kt += BK) {
        #pragma unroll
        for (int p = 0; p < 2; p++) {
            const int r = srow + p * 64;
            const int gm = bm + r;
            i32x4 va = {0, 0, 0, 0};
            if (gm < NN) va = *(const i32x4*)(A + (size_t)gm * 256 + kt + kseg);
            *(i32x4*)(&As[r * LDK + kseg]) = va;
            *(i32x4*)(&Bs[r * LDK + kseg]) =
                *(const i32x4*)(B + (size_t)(bn + r) * 256 + kt + kseg);
        }
        __syncthreads();

        f16x8 af[4], bfr[4];
        #pragma unroll
        for (int i = 0; i < 4; i++)
            af[i]  = *(const f16x8*)(&As[(wm + i * 16 + l16) * LDK + quad * 8]);
        #pragma unroll
        for (int j = 0; j < 4; j++)
            bfr[j] = *(const f16x8*)(&Bs[(wn + j * 16 + l16) * LDK + quad * 8]);
        #pragma unroll
        for (int i = 0; i < 4; i++)
            #pragma unroll
            for (int j = 0; j < 4; j++)
                acc[i][j] = __builtin_amdgcn_mfma_f32_16x16x32_f16(af[i], bfr[j], acc[i][j], 0, 0, 0);
        __syncthreads();
    }

    const int sector = bn >> 8;              // 0=q, 1=k, 2=v (BN=128 keeps a block within one sector)
    const int cbase  = (bn & 255) + wn;
    #pragma unroll
    for (int i = 0; i < 4; i++) {
        #pragma unroll
        for (int r = 0; r < 4; r++) {
            const int row = bm + wm + i * 16 + quad * 4 + r;
            if (row >= NN) continue;
            #pragma unroll
            for (int j = 0; j < 4; j++) {
                const int c = cbase + j * 16 + l16;
                const unsigned short val = f2h(acc[i][j][r]);
                if (sector == 0)      qv[(size_t)row * 512 + 2 * c]     = val;
                else if (sector == 1) kb[(size_t)row * 256 + c]         = val;
                else                  qv[(size_t)row * 512 + 2 * c + 1] = val;
            }
        }
    }
}

// ---------------- per-dst softmax + weighted aggregate ----------------
__global__ __launch_bounds__(256) void edge_kernel(const unsigned int* __restrict__ qv,   // [30000,256] packed {q,v} fp16
                                                   const unsigned short* __restrict__ kb,
                                                   const int* __restrict__ cursor,
                                                   const int* __restrict__ col,
                                                   float* __restrict__ out) {
    const int n = blockIdx.x;
    const int c = threadIdx.x;
    int deg = cursor[n];
    if (deg > CAP) deg = CAP;

    __shared__ int sidx[CAP];
    if (c < deg) sidx[c] = col[n * CAP + c];
    __syncthreads();

    const float kk = h2f(kb[n * 256 + c]) * SCALE;
    float z = 0.0f, acc = 0.0f;
    for (int i = 0; i < deg; ++i) {
        const unsigned int d = qv[(size_t)sidx[i] * 256 + c];
        union { unsigned int u; _Float16 h[2]; } cv;
        cv.u = d;
        const float qf = (float)cv.h[0];
        const float vf = (float)cv.h[1];
        const float w = __expf(qf * kk);
        z += w;
        acc += w * vf;
    }
    out[n * 256 + c] = (deg > 0) ? (acc / z) : 0.0f;
}

extern "C" void kernel_launch(void* const* d_in, const int* in_sizes, int n_in,
                              void* d_out, int out_size, void* d_ws, size_t ws_size,
                              hipStream_t stream) {
    const float* s     = (const float*)d_in[0];
    const float* Wqkv  = (const float*)d_in[1];
    const float* gamma = (const float*)d_in[2];
    const float* beta  = (const float*)d_in[3];
    const int*   src   = (const int*)d_in[4];
    const int*   dst   = (const int*)d_in[5];
    float* out = (float*)d_out;

    char* ws = (char*)d_ws;
    unsigned short* xh  = (unsigned short*)(ws);                    // 15,360,000 B
    unsigned short* WT  = (unsigned short*)(ws + 15360000);         //    393,216 B
    unsigned short* qv  = (unsigned short*)(ws + 15753216);         // 30,720,000 B
    unsigned short* kb  = (unsigned short*)(ws + 46473216);         // 15,360,000 B
    int*            cur = (int*)(ws + 61833216);                    //    120,000 B
    int*            col = (int*)(ws + 61953216);                    // 11,520,000 B (total ~73.5 MB)

    ln_kernel<<<NN, 256, 0, stream>>>(s, gamma, beta, xh);
    wt_kernel<<<(768 * 256 + 255) / 256, 256, 0, stream>>>(Wqkv, WT);
    zero_kernel<<<(NN + 255) / 256, 256, 0, stream>>>(cur, NN);
    scatter_kernel<<<(NE + 255) / 256, 256, 0, stream>>>(src, dst, cur, col);
    gemm_kernel<<<dim3((NN + BM - 1) / BM, 768 / BN), 256, 0, stream>>>(xh, WT, qv, kb);
    edge_kernel<<<NN, 256, 0, stream>>>((const unsigned int*)qv, kb, cur, col, out);
}